// Round 17
// baseline (80.721 us; speedup 1.0000x reference)
//
#include <hip/hip_runtime.h>

// GMLoss: bidirectional chamfer min + Geman-McClure penalty (MU=1).
// srcs, tgts: [B=8, D=3, N=4096] fp32. Output: scalar fp32.
//
// R17 = R14 (74.3us best) with the chamfer inner loop's instruction stream
// cut down. Evidence (R5: VALUBusy 41% x 51.5us ~= 21us busy vs ~5us source
// estimate) says the loop executes 3-4x the source VALU count (AGPR<->VGPR
// result moves + ring-copy movs). Mechanical cuts:
//  1. In-place prefetch ring: full unroll, each tile loads directly into
//     the slot just consumed (t[i&7]) -- no 8x V16 copy rotation per step.
//  2. Paired-tile processing with min3: rmin = fminf(rmin, fminf(dA,dB))
//     -> v_min3_f32, halving min instructions per pair.
//  3. Bounds (256,2) (R14's best), 4 row-tiles, K-replication unchanged.
// Per-tile VALU ~28 -> ~12 source instrs.
//
// Kept (absmax 0.0 since R6): K=13 hi/lo pack, K-replication (quads 2,3
// re-read bytes 0..31 -> D=2P, halve after min), plain stores + tiny finish
// (NO fences/hot atomics - R7/R9), XCD swizzle group=blk&15.
//   A k: [-2sh(3), -2sl(3), -2sh(3), s2h, s2l, 1, 1, 0,0,0]
//   B k: [ th(3),   th(3),   tl(3),  1, 1, t2h, t2l, 0,0,0]
//   dot = |s|^2+|t|^2-2s.t  (drops sl.tl ~1e-5 << 1.26e-3 threshold).
// 16x16x32 layouts (m89/m91): A[m=lane&15][k=(lane>>4)*8+j], B same
// (n=lane&15); D: col=lane&15, row=(lane>>4)*4+reg.

#define NPTS 4096
#define NB   8

typedef __attribute__((ext_vector_type(8))) short bf16x8;
typedef __attribute__((ext_vector_type(4))) float floatx4;

// ws layout: Apack[srcs], Apack[tgts], Bpack[srcs], Bpack[tgts], bsum[1024]
#define OFF_APACK_S 0u
#define OFF_APACK_T (1u << 20)
#define OFF_BPACK_S (2u << 20)
#define OFF_BPACK_T (3u << 20)
#define OFF_BSUM    (4u << 20)

union V16 { int4 i; bf16x8 h; };

__device__ __forceinline__ unsigned short f2bf(float f) {
    unsigned u = __float_as_uint(f);
    u += 0x7FFFu + ((u >> 16) & 1u);       // RNE
    return (unsigned short)(u >> 16);
}
__device__ __forceinline__ float bf2f(unsigned short h) {
    return __uint_as_float(((unsigned)h) << 16);
}
__device__ __forceinline__ int pk(unsigned short lo, unsigned short hi) {
    return (int)((unsigned)lo | ((unsigned)hi << 16));
}

// ---------------- Kernel 1: pack A-style + B-style, 1 point/thread --------
__device__ __forceinline__ void pack_point(const float* __restrict__ cloud,
                                           int b, int j, int gid,
                                           char* __restrict__ apack,
                                           char* __restrict__ bpack) {
    const unsigned short ONE = 0x3F80;
    const float* p = cloud + b * 3 * NPTS;
    const float x = p[j], y = p[NPTS + j], z = p[2 * NPTS + j];
    const unsigned short hx = f2bf(x), hy = f2bf(y), hz = f2bf(z);
    const unsigned short lx = f2bf(x - bf2f(hx));
    const unsigned short ly = f2bf(y - bf2f(hy));
    const unsigned short lz = f2bf(z - bf2f(hz));
    const unsigned short a0 = f2bf(-2.0f * bf2f(hx));
    const unsigned short a1 = f2bf(-2.0f * bf2f(hy));
    const unsigned short a2 = f2bf(-2.0f * bf2f(hz));
    const unsigned short m0 = f2bf(-2.0f * (x - bf2f(hx)));
    const unsigned short m1 = f2bf(-2.0f * (y - bf2f(hy)));
    const unsigned short m2 = f2bf(-2.0f * (z - bf2f(hz)));
    const float n2 = fmaf(z, z, fmaf(y, y, x * x));
    const unsigned short n2h = f2bf(n2);
    const unsigned short n2l = f2bf(n2 - bf2f(n2h));

    int4* Ap = (int4*)(apack + (size_t)gid * 32);
    Ap[0] = make_int4(pk(a0, a1), pk(a2, m0), pk(m1, m2), pk(a0, a1));
    Ap[1] = make_int4(pk(a2, n2h), pk(n2l, ONE), pk(ONE, 0), 0);

    int4* Bp = (int4*)(bpack + (size_t)gid * 32);
    Bp[0] = make_int4(pk(hx, hy), pk(hz, hx), pk(hy, hz), pk(lx, ly));
    Bp[1] = make_int4(pk(lz, ONE), pk(ONE, n2h), pk(n2l, 0), 0);
}

__global__ __launch_bounds__(256)
void transform_kernel(const float* __restrict__ srcs,
                      const float* __restrict__ tgts,
                      char* __restrict__ ws) {
    const int gid = blockIdx.x * 256 + threadIdx.x;   // 0..65535
    const int dir = gid >> 15;
    const int rem = gid & 32767;                      // b*4096 + j
    const int b = rem >> 12, j = rem & 4095;
    if (dir == 0)
        pack_point(srcs, b, j, rem, ws + OFF_APACK_S, ws + OFF_BPACK_S);
    else
        pack_point(tgts, b, j, rem, ws + OFF_APACK_T, ws + OFF_BPACK_T);
}

// ---------------- Kernel 2: row-min MFMA chamfer (16x16x32, 64 rows) ------
__global__ __launch_bounds__(256, 2)
void chamfer_kernel(char* __restrict__ ws) {
    const int blk    = blockIdx.x;        // 0..1023
    const int group  = blk & 15;          // XCD-aware swizzle
    const int dir    = group >> 3;
    const int b      = group & 7;
    const int stripe = blk >> 4;          // 0..63, 64 query rows each
    const int tid    = threadIdx.x;
    const int wave   = tid >> 6;          // 0..3
    const int lane   = tid & 63;
    const int l15    = lane & 15;
    const int quad   = lane >> 4;         // k-half = (quad&1)*16 bytes

    const char* Ap = ws + (dir == 0 ? OFF_APACK_S : OFF_APACK_T);
    const char* Bp = ws + (dir == 0 ? OFF_BPACK_T : OFF_BPACK_S);

    // 4 row-tiles of 16 rows; quads 2,3 replicate quads 0,1 -> D = 2P.
    V16 av[4];
#pragma unroll
    for (int rt = 0; rt < 4; rt++)
        av[rt].i = *(const int4*)(Ap +
            (size_t)(b * NPTS + stripe * 64 + rt * 16 + l15) * 32 + (quad & 1) * 16);

    floatx4 rmin[4];
#pragma unroll
    for (int rt = 0; rt < 4; rt++)
        rmin[rt] = (floatx4){3.0e38f, 3.0e38f, 3.0e38f, 3.0e38f};
    const floatx4 zero = {0.0f, 0.0f, 0.0f, 0.0f};

    const int ct0 = wave * 64;            // 64 col-tiles (of 16 pts) per wave
    const char* bbase = Bp + (size_t)(b * NPTS + ct0 * 16 + l15) * 32 + (quad & 1) * 16;

    // depth-8 in-place prefetch ring over 64 tiles, 512 B apart; wrap &63.
    V16 t[8];
#pragma unroll
    for (int k = 0; k < 8; k++)
        t[k].i = *(const int4*)(bbase + (size_t)k * 512);

#pragma unroll
    for (int i = 0; i < 64; i += 2) {
        const bf16x8 bfA = t[i & 7].h;
        const bf16x8 bfB = t[(i + 1) & 7].h;
        floatx4 dA[4], dB[4];
#pragma unroll
        for (int rt = 0; rt < 4; rt++) {
            dA[rt] = __builtin_amdgcn_mfma_f32_16x16x32_bf16(av[rt].h, bfA, zero, 0, 0, 0);
            dB[rt] = __builtin_amdgcn_mfma_f32_16x16x32_bf16(av[rt].h, bfB, zero, 0, 0, 0);
        }
        // reload the two consumed slots with tiles i+8, i+9 (in-place, no copies)
        t[i & 7].i       = *(const int4*)(bbase + (size_t)((i + 8) & 63) * 512);
        t[(i + 1) & 7].i = *(const int4*)(bbase + (size_t)((i + 9) & 63) * 512);
#pragma unroll
        for (int rt = 0; rt < 4; rt++)
#pragma unroll
            for (int r = 0; r < 4; r++)   // v_min3: rmin = min(rmin, dA, dB)
                rmin[rt][r] = fminf(rmin[rt][r], fminf(dA[rt][r], dB[rt][r]));
    }

    // ---- butterfly min over the 16 col-lanes ----
#pragma unroll
    for (int off = 1; off < 16; off <<= 1) {
#pragma unroll
        for (int rt = 0; rt < 4; rt++)
#pragma unroll
            for (int r = 0; r < 4; r++)
                rmin[rt][r] = fminf(rmin[rt][r], __shfl_xor(rmin[rt][r], off, 64));
    }
    // quad leader holds rows rt*16 + quad*4 + r
    __shared__ float sRow[4][64];
    if (l15 == 0) {
#pragma unroll
        for (int rt = 0; rt < 4; rt++)
#pragma unroll
            for (int r = 0; r < 4; r++)
                sRow[wave][rt * 16 + quad * 4 + r] = rmin[rt][r];
    }
    __syncthreads();
    if (tid < 64) {
        float m = fminf(fminf(sRow[0][tid], sRow[1][tid]),
                        fminf(sRow[2][tid], sRow[3][tid]));
        m = fmaxf(m * 0.5f, 0.0f);        // undo K-replication doubling
        float g = m / (m + 1.0f);         // GM, MU=1
#pragma unroll
        for (int off = 1; off < 64; off <<= 1)
            g += __shfl_xor(g, off, 64);
        if (tid == 0)
            ((float*)(ws + OFF_BSUM))[blk] = g;   // plain store
    }
}

// ---------------- Kernel 3: single-block finish ----------------
__global__ __launch_bounds__(256)
void finish_kernel(const char* __restrict__ ws, float* __restrict__ out) {
    const float* bsum = (const float*)(ws + OFF_BSUM);
    const int tid = threadIdx.x;
    float g = bsum[tid] + bsum[tid + 256] + bsum[tid + 512] + bsum[tid + 768];
#pragma unroll
    for (int off = 1; off < 64; off <<= 1)
        g += __shfl_xor(g, off, 64);
    __shared__ float sp[4];
    if ((tid & 63) == 0) sp[tid >> 6] = g;
    __syncthreads();
    if (tid == 0)
        out[0] = (sp[0] + sp[1] + sp[2] + sp[3]) * (1.0f / (NB * NPTS));
}

extern "C" void kernel_launch(void* const* d_in, const int* in_sizes, int n_in,
                              void* d_out, int out_size, void* d_ws, size_t ws_size,
                              hipStream_t stream) {
    const float* srcs = (const float*)d_in[0];
    const float* tgts = (const float*)d_in[1];
    float* out = (float*)d_out;
    char* ws = (char*)d_ws;

    transform_kernel<<<dim3(256), dim3(256), 0, stream>>>(srcs, tgts, ws);
    chamfer_kernel<<<dim3(1024), dim3(256), 0, stream>>>(ws);
    finish_kernel<<<dim3(1), dim3(256), 0, stream>>>(ws, out);
}

// Round 18
// 73.042 us; speedup vs baseline: 1.1051x; 1.1051x over previous
//
#include <hip/hip_runtime.h>

// GMLoss: bidirectional chamfer min + Geman-McClure penalty (MU=1).
// srcs, tgts: [B=8, D=3, N=4096] fp32. Output: scalar fp32.
//
// FINAL = R14 (measured best: 74.3us). Structure and why (18 rounds):
//  - transform: fp32 -> K=13 hi/lo bf16 MFMA packing for both clouds
//    (A-style + B-style), 1 point/thread.
//  - chamfer: 16x16x32 bf16 MFMA, K-replication (quads 2,3 re-read bytes
//    0..31 -> D=2P, halve after min), 64 query rows/block, depth-4 register
//    prefetch ring, XCD swizzle group=blk&15, per-block GM partials via
//    PLAIN STORES to bsum.
//  - finish: 1-block reduce of bsum -> scalar.
// Hard-won constraints (counter-evidenced):
//  - NO device-scope fences or bulk atomics in hot kernels (R7: 2M atomicMin
//    -> 478MB RMW traffic, 263us; R9: per-block __threadfence -> 70us floor).
//  - __launch_bounds__(256,2): cap-128 squeezes spill scratch (R13: VGPR=64,
//    WRITE 244MB, 159us); floatx16 accs at low caps get AGPR-exiled (R12).
//  - Neutral when tested around this structure: 32x32x16 shape (R15),
//    depth-8 ring + (256,4) (R16), in-place ring + min3 (R17), XCD swizzle
//    granularity (R10/R11 delta ~= 0).
// Accuracy: K=13 pack gives |s|^2+|t|^2-2s.t with only sl.tl dropped
// (~1e-5 << 1.26e-3 threshold); absmax 0.0 on every round since R6.
//   A k: [-2sh(3), -2sl(3), -2sh(3), s2h, s2l, 1, 1, 0,0,0]
//   B k: [ th(3),   th(3),   tl(3),  1, 1, t2h, t2l, 0,0,0]
// 16x16x32 layouts (m89/m91): A[m=lane&15][k=(lane>>4)*8+j], B same
// (n=lane&15); D: col=lane&15, row=(lane>>4)*4+reg.
// Budget at ceiling: ~40.5us harness d_ws re-poison (268MB fill, timed) +
// ~34us kernels; kernel portion plateaued across 4 orthogonal families.

#define NPTS 4096
#define NB   8

typedef __attribute__((ext_vector_type(8))) short bf16x8;
typedef __attribute__((ext_vector_type(4))) float floatx4;

// ws layout: Apack[srcs], Apack[tgts], Bpack[srcs], Bpack[tgts], bsum[1024]
#define OFF_APACK_S 0u
#define OFF_APACK_T (1u << 20)
#define OFF_BPACK_S (2u << 20)
#define OFF_BPACK_T (3u << 20)
#define OFF_BSUM    (4u << 20)

union V16 { int4 i; bf16x8 h; };

__device__ __forceinline__ unsigned short f2bf(float f) {
    unsigned u = __float_as_uint(f);
    u += 0x7FFFu + ((u >> 16) & 1u);       // RNE
    return (unsigned short)(u >> 16);
}
__device__ __forceinline__ float bf2f(unsigned short h) {
    return __uint_as_float(((unsigned)h) << 16);
}
__device__ __forceinline__ int pk(unsigned short lo, unsigned short hi) {
    return (int)((unsigned)lo | ((unsigned)hi << 16));
}

// ---------------- Kernel 1: pack A-style + B-style, 1 point/thread --------
__device__ __forceinline__ void pack_point(const float* __restrict__ cloud,
                                           int b, int j, int gid,
                                           char* __restrict__ apack,
                                           char* __restrict__ bpack) {
    const unsigned short ONE = 0x3F80;
    const float* p = cloud + b * 3 * NPTS;
    const float x = p[j], y = p[NPTS + j], z = p[2 * NPTS + j];
    const unsigned short hx = f2bf(x), hy = f2bf(y), hz = f2bf(z);
    const unsigned short lx = f2bf(x - bf2f(hx));
    const unsigned short ly = f2bf(y - bf2f(hy));
    const unsigned short lz = f2bf(z - bf2f(hz));
    const unsigned short a0 = f2bf(-2.0f * bf2f(hx));
    const unsigned short a1 = f2bf(-2.0f * bf2f(hy));
    const unsigned short a2 = f2bf(-2.0f * bf2f(hz));
    const unsigned short m0 = f2bf(-2.0f * (x - bf2f(hx)));
    const unsigned short m1 = f2bf(-2.0f * (y - bf2f(hy)));
    const unsigned short m2 = f2bf(-2.0f * (z - bf2f(hz)));
    const float n2 = fmaf(z, z, fmaf(y, y, x * x));
    const unsigned short n2h = f2bf(n2);
    const unsigned short n2l = f2bf(n2 - bf2f(n2h));

    int4* Ap = (int4*)(apack + (size_t)gid * 32);
    Ap[0] = make_int4(pk(a0, a1), pk(a2, m0), pk(m1, m2), pk(a0, a1));
    Ap[1] = make_int4(pk(a2, n2h), pk(n2l, ONE), pk(ONE, 0), 0);

    int4* Bp = (int4*)(bpack + (size_t)gid * 32);
    Bp[0] = make_int4(pk(hx, hy), pk(hz, hx), pk(hy, hz), pk(lx, ly));
    Bp[1] = make_int4(pk(lz, ONE), pk(ONE, n2h), pk(n2l, 0), 0);
}

__global__ __launch_bounds__(256)
void transform_kernel(const float* __restrict__ srcs,
                      const float* __restrict__ tgts,
                      char* __restrict__ ws) {
    const int gid = blockIdx.x * 256 + threadIdx.x;   // 0..65535
    const int dir = gid >> 15;
    const int rem = gid & 32767;                      // b*4096 + j
    const int b = rem >> 12, j = rem & 4095;
    if (dir == 0)
        pack_point(srcs, b, j, rem, ws + OFF_APACK_S, ws + OFF_BPACK_S);
    else
        pack_point(tgts, b, j, rem, ws + OFF_APACK_T, ws + OFF_BPACK_T);
}

// ---------------- Kernel 2: row-min MFMA chamfer (16x16x32, 64 rows) ------
__global__ __launch_bounds__(256, 2)
void chamfer_kernel(char* __restrict__ ws) {
    const int blk    = blockIdx.x;        // 0..1023
    const int group  = blk & 15;          // XCD-aware swizzle
    const int dir    = group >> 3;
    const int b      = group & 7;
    const int stripe = blk >> 4;          // 0..63, 64 query rows each
    const int tid    = threadIdx.x;
    const int wave   = tid >> 6;          // 0..3
    const int lane   = tid & 63;
    const int l15    = lane & 15;
    const int quad   = lane >> 4;         // k-half = (quad&1)*16 bytes

    const char* Ap = ws + (dir == 0 ? OFF_APACK_S : OFF_APACK_T);
    const char* Bp = ws + (dir == 0 ? OFF_BPACK_T : OFF_BPACK_S);

    // 4 row-tiles of 16 rows; quads 2,3 replicate quads 0,1 -> D = 2P.
    V16 av[4];
#pragma unroll
    for (int rt = 0; rt < 4; rt++)
        av[rt].i = *(const int4*)(Ap +
            (size_t)(b * NPTS + stripe * 64 + rt * 16 + l15) * 32 + (quad & 1) * 16);

    floatx4 rmin[4];
#pragma unroll
    for (int rt = 0; rt < 4; rt++)
        rmin[rt] = (floatx4){3.0e38f, 3.0e38f, 3.0e38f, 3.0e38f};
    const floatx4 zero = {0.0f, 0.0f, 0.0f, 0.0f};

    const int ct0 = wave * 64;            // 64 col-tiles (of 16 pts) per wave
    const char* bbase = Bp + (size_t)(b * NPTS + ct0 * 16 + l15) * 32 + (quad & 1) * 16;

    // depth-4 register prefetch ring over 64 tiles, 512 B apart; wrap &63
    V16 t0, t1, t2, t3;
    t0.i = *(const int4*)(bbase);
    t1.i = *(const int4*)(bbase + 512);
    t2.i = *(const int4*)(bbase + 1024);
    t3.i = *(const int4*)(bbase + 1536);

#pragma unroll
    for (int i = 0; i < 64; i += 4) {
        V16 n0, n1, n2, n3;
        n0.i = *(const int4*)(bbase + (size_t)((i + 4) & 63) * 512);
        n1.i = *(const int4*)(bbase + (size_t)((i + 5) & 63) * 512);
        n2.i = *(const int4*)(bbase + (size_t)((i + 6) & 63) * 512);
        n3.i = *(const int4*)(bbase + (size_t)((i + 7) & 63) * 512);
#pragma unroll
        for (int u = 0; u < 4; u++) {
            const bf16x8 bf = (u == 0 ? t0.h : u == 1 ? t1.h : u == 2 ? t2.h : t3.h);
#pragma unroll
            for (int rt = 0; rt < 4; rt++) {
                const floatx4 d =
                    __builtin_amdgcn_mfma_f32_16x16x32_bf16(av[rt].h, bf, zero, 0, 0, 0);
#pragma unroll
                for (int r = 0; r < 4; r++)
                    rmin[rt][r] = fminf(rmin[rt][r], d[r]);
            }
        }
        t0 = n0; t1 = n1; t2 = n2; t3 = n3;
    }

    // ---- butterfly min over the 16 col-lanes ----
#pragma unroll
    for (int off = 1; off < 16; off <<= 1) {
#pragma unroll
        for (int rt = 0; rt < 4; rt++)
#pragma unroll
            for (int r = 0; r < 4; r++)
                rmin[rt][r] = fminf(rmin[rt][r], __shfl_xor(rmin[rt][r], off, 64));
    }
    // quad leader holds rows rt*16 + quad*4 + r
    __shared__ float sRow[4][64];
    if (l15 == 0) {
#pragma unroll
        for (int rt = 0; rt < 4; rt++)
#pragma unroll
            for (int r = 0; r < 4; r++)
                sRow[wave][rt * 16 + quad * 4 + r] = rmin[rt][r];
    }
    __syncthreads();
    if (tid < 64) {
        float m = fminf(fminf(sRow[0][tid], sRow[1][tid]),
                        fminf(sRow[2][tid], sRow[3][tid]));
        m = fmaxf(m * 0.5f, 0.0f);        // undo K-replication doubling
        float g = m / (m + 1.0f);         // GM, MU=1
#pragma unroll
        for (int off = 1; off < 64; off <<= 1)
            g += __shfl_xor(g, off, 64);
        if (tid == 0)
            ((float*)(ws + OFF_BSUM))[blk] = g;   // plain store
    }
}

// ---------------- Kernel 3: single-block finish ----------------
__global__ __launch_bounds__(256)
void finish_kernel(const char* __restrict__ ws, float* __restrict__ out) {
    const float* bsum = (const float*)(ws + OFF_BSUM);
    const int tid = threadIdx.x;
    float g = bsum[tid] + bsum[tid + 256] + bsum[tid + 512] + bsum[tid + 768];
#pragma unroll
    for (int off = 1; off < 64; off <<= 1)
        g += __shfl_xor(g, off, 64);
    __shared__ float sp[4];
    if ((tid & 63) == 0) sp[tid >> 6] = g;
    __syncthreads();
    if (tid == 0)
        out[0] = (sp[0] + sp[1] + sp[2] + sp[3]) * (1.0f / (NB * NPTS));
}

extern "C" void kernel_launch(void* const* d_in, const int* in_sizes, int n_in,
                              void* d_out, int out_size, void* d_ws, size_t ws_size,
                              hipStream_t stream) {
    const float* srcs = (const float*)d_in[0];
    const float* tgts = (const float*)d_in[1];
    float* out = (float*)d_out;
    char* ws = (char*)d_ws;

    transform_kernel<<<dim3(256), dim3(256), 0, stream>>>(srcs, tgts, ws);
    chamfer_kernel<<<dim3(1024), dim3(256), 0, stream>>>(ws);
    finish_kernel<<<dim3(1), dim3(256), 0, stream>>>(ws, out);
}